// Round 12
// baseline (548.118 us; speedup 1.0000x reference)
//
#include <hip/hip_runtime.h>
#include <math.h>

// ---------------------------------------------------------------------------
// GAT 3-layer + pooling. XCD-sharded gather + XOR-swizzled GEMM LDS.
//  - agg v10 (this round): edge softmax FUSED into the gather. The separate
//    edge_weight pass (3 dispatches ~50us, wp 23MB traffic) is deleted: while
//    prefetching edge base+j, lane j loads csr_src, gathers el8[src*8+head]
//    (640KB, L2-resident), adds cluster-uniform er8[v], leaky+expf, packs
//    (src|f16(w)<<16) in-register (same broadcast path as before) and
//    accumulates sum(w) in fp32; 3 intra-cluster shfl_xors give inv locally.
//  - prep v1 (r11): all independent preprocessing in ONE dispatch.
//  - GEMM v4 (r10): BM=64 x BN=128 tiles; 2x2 waves over 32x64 sub-tiles;
//    2-buffer STAGE-before-compute; m204 XCD swizzle.
//  - L2 residual FOLDED (r8): mean_h(res2) == x2 @ resW2m; L2 GEMM N=896.
//  - graph_pool: 1024-thr 8-way reduce, final MLP fused.
//  - feat CHUNK-MAJOR featc[chunk][node][64]; chunk=blockIdx%8 -> XCD-pinned L2.
//  - attn logits fused in GEMM epilogue; pooling segmented (gid sorted).
// ---------------------------------------------------------------------------

typedef _Float16 f16;
typedef __attribute__((ext_vector_type(8))) _Float16 half8;
typedef __attribute__((ext_vector_type(4))) _Float16 half4;
typedef __attribute__((ext_vector_type(4))) float float4v;

union U16 { unsigned short u; _Float16 h; };

#define M_PAD 20096        // 20000 rounded up to 128 (and to 64)
#define CHSTRIDE ((size_t)M_PAD * 64)

__device__ inline void gload_lds16(const void* g, void* l) {
    __builtin_amdgcn_global_load_lds((const __attribute__((address_space(1))) unsigned*)g,
                                     (__attribute__((address_space(3))) unsigned*)l,
                                     16, 0, 0);
}

// ----------------------------- CSR construction ---------------------------

__global__ __launch_bounds__(256) void deg_kernel(const int* __restrict__ dst,
                                                  int* __restrict__ deg, int E) {
    int e = blockIdx.x * 256 + threadIdx.x;
    if (e < E) atomicAdd(&deg[dst[e]], 1);
}

// scan + (fused) graph-segment binary search
__global__ __launch_bounds__(1024) void scan_kernel(const int* __restrict__ deg,
                                                    int* __restrict__ row_off,
                                                    const int* __restrict__ gid,
                                                    int* __restrict__ gstart, int n) {
    __shared__ int sums[1024];
    int t = threadIdx.x;
    if (t <= 64) {
        int g = t, lo = 0, hi = n;
        while (lo < hi) {
            int mid = (lo + hi) >> 1;
            if (gid[mid] < g) lo = mid + 1; else hi = mid;
        }
        gstart[g] = lo;
    }
    int CH = (n + 1023) >> 10;
    int base = t * CH;
    int s = 0;
    for (int i = 0; i < CH; ++i) { int idx = base + i; if (idx < n) s += deg[idx]; }
    sums[t] = s;
    __syncthreads();
    for (int off = 1; off < 1024; off <<= 1) {
        int v = (t >= off) ? sums[t - off] : 0;
        __syncthreads();
        sums[t] += v;
        __syncthreads();
    }
    int run = (t == 0) ? 0 : sums[t - 1];
    for (int i = 0; i < CH; ++i) {
        int idx = base + i;
        if (idx < n) { row_off[idx] = run; run += deg[idx]; }
    }
    if (t == 1023) row_off[n] = run;
}

__global__ __launch_bounds__(256) void fill_kernel(const int* __restrict__ src,
                                                   const int* __restrict__ dst,
                                                   const int* __restrict__ row_off,
                                                   int* __restrict__ fill,
                                                   int* __restrict__ csr_src, int E) {
    int e = blockIdx.x * 256 + threadIdx.x;
    if (e < E) {
        int d = dst[e];
        int pos = row_off[d] + atomicAdd(&fill[d], 1);
        csr_src[pos] = src[e];
    }
}

// ------------------- fused preprocessing (one dispatch) --------------------
// blockIdx ranges:
//   [0,2512)      cvt_pad: h (fp32) -> h16, zero rows >= n   (M_PAD*128/1024)
//   [2512,2560)   zero_pad rows [n,M_PAD) of x1,x2 (512 cols)
//   [2560,2624)   transpose W0  (512/32 x 128/32)
//   [2624,2880)   transpose W1  (512/32 x 512/32)
//   [2880,3264)   transpose W2  (768/32 x 512/32) -> Wt2cat[0:768]
//   [3264,3520)   fold_res: resW2m^T -> Wt2cat[768:896]
//   [3520,3560)   zero deg|fillc (2n ints, int4)

__global__ __launch_bounds__(256) void prep_kernel(
        const float* __restrict__ h, f16* __restrict__ h16,
        f16* __restrict__ x1, f16* __restrict__ x2,
        const float* __restrict__ W0, f16* __restrict__ Wt0,
        const float* __restrict__ W1, f16* __restrict__ Wt1,
        const float* __restrict__ W2, const float* __restrict__ resW2,
        f16* __restrict__ Wt2cat,
        int* __restrict__ deg2, int n) {
    __shared__ float tile[32][33];
    int b = blockIdx.x;
    int t = threadIdx.x;
    if (b < 2512) {               // cvt_pad
        long i = ((long)b * 256 + t) * 4;
        long nv = (long)n * 128;
        float4 v = make_float4(0.f, 0.f, 0.f, 0.f);
        if (i < nv) v = *(const float4*)&h[i];
        half4 o; o[0] = (f16)v.x; o[1] = (f16)v.y; o[2] = (f16)v.z; o[3] = (f16)v.w;
        *(half4*)&h16[i] = o;
        return;
    }
    b -= 2512;
    if (b < 48) {                 // zero_pad x1/x2
        int idx = (b * 256 + t) * 4;
        int total = (M_PAD - n) * 512;
        if (idx < total) {
            half4 z; z[0] = (f16)0.f; z[1] = (f16)0.f; z[2] = (f16)0.f; z[3] = (f16)0.f;
            *(half4*)&x1[(size_t)n * 512 + idx] = z;
            *(half4*)&x2[(size_t)n * 512 + idx] = z;
        }
        return;
    }
    b -= 48;
    {   // transposes: W0 (64 blk), W1 (256 blk), W2 (384 blk)
        const float* W = nullptr; f16* Wt = nullptr;
        int K = 0, N = 0, bx = 0, by = 0;
        bool dotr = false;
        if (b < 64)        { W = W0; Wt = Wt0;    K = 128; N = 512; bx = b & 15;  by = b >> 4; dotr = true; }
        else if (b < 320)  { int r = b - 64;  W = W1; Wt = Wt1;    K = 512; N = 512; bx = r & 15;  by = r >> 4; dotr = true; }
        else if (b < 704)  { int r = b - 320; W = W2; Wt = Wt2cat; K = 512; N = 768; bx = r % 24;  by = r / 24; dotr = true; }
        if (dotr) {
            int tx = t & 31, ty = t >> 5;
            int n0 = bx * 32, k0 = by * 32;
#pragma unroll
            for (int i = 0; i < 32; i += 8)
                tile[ty + i][tx] = W[(size_t)(k0 + ty + i) * N + n0 + tx];
            __syncthreads();
#pragma unroll
            for (int i = 0; i < 32; i += 8)
                Wt[(size_t)(n0 + ty + i) * K + k0 + tx] = (f16)tile[tx][ty + i];
            return;
        }
    }
    b -= 704;
    if (b < 256) {                // fold_res
        int idx = b * 256 + t;
        int d = idx >> 9;          // 0..127
        int k = idx & 511;         // 0..511
        float s = 0.f;
#pragma unroll
        for (int hh = 0; hh < 6; ++hh) s += resW2[(size_t)k * 768 + hh * 128 + d];
        Wt2cat[(size_t)(768 + d) * 512 + k] = (f16)(s * (1.f / 6.f));
        return;
    }
    b -= 256;
    {                             // zero deg|fillc
        int idx = (b * 256 + t) * 4;
        if (idx < 2 * n) *(int4*)&deg2[idx] = make_int4(0, 0, 0, 0);
    }
}

// ------------------------------ fp16 MFMA GEMM -----------------------------
// BM=64 x BN=128 tile, 4 waves as 2(M) x 2(N) over 32x64 sub-tiles.
// LDS: As[64][32], Bs[128][32] per buffer, octets XOR-swizzled within rows:
//   slot s of row r holds global octet s ^ ((r>>1)&3).
// Staging: lane t -> row t>>2, slot t&3 -> stages octet (t&3)^((row>>1)&3);
//   A = 1 gload/thread (64 rows), B = 2 gloads (128 rows).
// Frag read: lane (ml,q) reads slot q^((ml>>1)&3); swizzle invariant under
//   +16/+32/+64 row offsets (all ≡ 0 mod 4 after >>1).
// Pipeline: double-buffered; STAGE(t+1) issued before compute(t); one barrier
// per K-step.

#define STAGE(buf, k0) do {                                   \
    f16* a_ = As + (buf) * 2048 + t * 8;                      \
    f16* b_ = Bs + (buf) * 4096 + t * 8;                      \
    gload_lds16(ag0 + (k0), a_);                              \
    gload_lds16(bg0 + (k0), b_);                              \
    gload_lds16(bg1 + (k0), b_ + 2048);                       \
} while (0)

__global__ __launch_bounds__(256) void gemm16_kernel(const f16* __restrict__ A,
                                                     const f16* __restrict__ Bt,
                                                     f16* __restrict__ Cc,
                                                     f16* __restrict__ Cr,
                                                     const float* __restrict__ al,
                                                     const float* __restrict__ ar,
                                                     float* __restrict__ el8,
                                                     float* __restrict__ er8,
                                                     int N, int K, int nchunk,
                                                     int nheads, int nvalid) {
    __shared__ f16 As[2 * 64 * 32];
    __shared__ f16 Bs[2 * 128 * 32];
    __shared__ float elds[2][2][64];   // [el/er][wn-half][row]
    int t = threadIdx.x;
    int w = t >> 6;
    int l = t & 63;

    // m204 bijective XCD swizzle
    int gx = gridDim.x;
    int nwg = gx * gridDim.y;
    int wg = blockIdx.y * gx + blockIdx.x;
    int qq = nwg >> 3, rr = nwg & 7;
    int xcd = wg & 7, idx = wg >> 3;
    int swz = (xcd < rr ? xcd * (qq + 1) : rr * (qq + 1) + (xcd - rr) * qq) + idx;
    int bxi = swz % gx;
    int byi = swz / gx;

    size_t bm = (size_t)byi * 64;
    int bn = bxi * 128;
    int wm = (w & 1) * 32;
    int wn = (w >> 1) * 64;

    int srow = t >> 2;                        // 0..63
    int sq = (t & 3) ^ ((srow >> 1) & 3);     // swizzled octet to stage
    const f16* ag0 = A + (bm + srow) * K + sq * 8;
    const f16* bg0 = Bt + (size_t)(bn + srow) * K + sq * 8;
    const f16* bg1 = Bt + (size_t)(bn + 64 + srow) * K + sq * 8;  // (64+r)>>1 ≡ r>>1 mod 4

    float4v acc[2][4];
#pragma unroll
    for (int i = 0; i < 2; ++i)
#pragma unroll
        for (int j = 0; j < 4; ++j) acc[i][j] = (float4v)(0.f);

    int ml = l & 15, q = l >> 4;
    int sslot = (q ^ ((ml >> 1) & 3)) * 8;    // swizzled read slot (f16 offset)
    int apoff = (wm + ml) * 32 + sslot;
    int bpoff = (wn + ml) * 32 + sslot;

    // prologue: stage tile 0, drain, flip into main loop
    STAGE(0, 0);
    __syncthreads();
    int cur = 0;
    for (int k0 = 0; k0 < K; k0 += 32) {
        if (k0 + 32 < K) STAGE(cur ^ 1, k0 + 32);   // issue next-tile loads FIRST
        const f16* ap = As + cur * 2048 + apoff;
        const f16* bp = Bs + cur * 4096 + bpoff;
        half8 af[2], bf[4];
#pragma unroll
        for (int mt = 0; mt < 2; ++mt) af[mt] = *(const half8*)(ap + mt * 16 * 32);
#pragma unroll
        for (int nt = 0; nt < 4; ++nt) bf[nt] = *(const half8*)(bp + nt * 16 * 32);
#pragma unroll
        for (int mt = 0; mt < 2; ++mt)
#pragma unroll
            for (int nt = 0; nt < 4; ++nt)
                acc[mt][nt] = __builtin_amdgcn_mfma_f32_16x16x32_f16(bf[nt], af[mt],
                                                                     acc[mt][nt], 0, 0, 0);
        __syncthreads();
        cur ^= 1;
    }
    // C stores
#pragma unroll
    for (int mt = 0; mt < 2; ++mt) {
        size_t row = bm + wm + mt * 16 + ml;
#pragma unroll
        for (int nt = 0; nt < 4; ++nt) {
            half4 hv;
#pragma unroll
            for (int r = 0; r < 4; ++r) hv[r] = (f16)acc[mt][nt][r];
            int col = bn + wn + nt * 16 + q * 4;
            if (col < nchunk) {
                *(half4*)&Cc[(size_t)(col >> 6) * CHSTRIDE + row * 64 + (col & 63)] = hv;
            } else {
                *(half4*)&Cr[row * (size_t)(N - nchunk) + (col - nchunk)] = hv;
            }
        }
    }
    // fused attention logits (block column == one head)
    if (al != nullptr && bn < nheads * 128) {
        int hh = bn >> 7;
        float4 a4[4], r4[4];
#pragma unroll
        for (int nt = 0; nt < 4; ++nt) {
            int ci = hh * 128 + wn + nt * 16 + q * 4;
            a4[nt] = *(const float4*)&al[ci];
            r4[nt] = *(const float4*)&ar[ci];
        }
        int wnidx = wn >> 6;
#pragma unroll
        for (int mt = 0; mt < 2; ++mt) {
            float ep = 0.f, rp = 0.f;
#pragma unroll
            for (int nt = 0; nt < 4; ++nt) {
                ep += acc[mt][nt][0] * a4[nt].x + acc[mt][nt][1] * a4[nt].y
                    + acc[mt][nt][2] * a4[nt].z + acc[mt][nt][3] * a4[nt].w;
                rp += acc[mt][nt][0] * r4[nt].x + acc[mt][nt][1] * r4[nt].y
                    + acc[mt][nt][2] * r4[nt].z + acc[mt][nt][3] * r4[nt].w;
            }
            ep += __shfl_xor(ep, 16, 64); ep += __shfl_xor(ep, 32, 64);
            rp += __shfl_xor(rp, 16, 64); rp += __shfl_xor(rp, 32, 64);
            if (q == 0) {
                elds[0][wnidx][wm + mt * 16 + ml] = ep;
                elds[1][wnidx][wm + mt * 16 + ml] = rp;
            }
        }
        __syncthreads();
        if (((t >> 6) & 1) == 0) {
            int row = t & 63, which = t >> 7;
            long gv = (long)bm + row;
            if (gv < nvalid) {
                float vs = elds[which][0][row] + elds[which][1][row];
                if (which == 0) el8[gv * 8 + hh] = vs;
                else            er8[gv * 8 + hh] = vs;
            }
        }
    }
}

// --- chunk-sharded aggregation v10: softmax weights fused into gather ------
// Per cluster (8 lanes, one node v, head = chunk>>1): lane j computes the
// weight of edge (base+j) while PREFETCHING it: load csr_src, gather
// el8[src*8+head] (L2-resident), add uniform er8[v*8+head], leaky+expf,
// pack (src | f16(w)<<16). Full-precision w accumulates into a per-lane
// lsum; 3 intra-cluster shfl_xors give sum(w) -> inv computed locally.

__device__ __forceinline__ void agg_chunk_body(
        const f16* __restrict__ fc, const int* __restrict__ csr_src,
        const float* __restrict__ el8, const float* __restrict__ er8, int head,
        const int* __restrict__ row_off,
        const f16* __restrict__ res, const float* __restrict__ bias,
        f16* __restrict__ out16, float* __restrict__ out32,
        int n, int width, int act, int chunk,
        int wave_id, int wavestride, int lane) {
    int c = lane >> 3;
    int j = lane & 7;
    int coff = j * 8;
    int cb = chunk * 64 + coff;
    float4 bv0 = *(const float4*)&bias[cb];
    float4 bv1 = *(const float4*)&bias[cb + 4];
    int clbase = lane & 56;

    for (int v0 = wave_id * 8; v0 < n; v0 += wavestride * 8) {
        int v = v0 + c;
        bool valid = (v < n);
        int beg = 0, end = 0;
        if (valid) { beg = row_off[v]; end = row_off[v + 1]; }
        int rounds = end - beg;
        rounds = max(rounds, __shfl_xor(rounds, 8, 64));
        rounds = max(rounds, __shfl_xor(rounds, 16, 64));
        rounds = max(rounds, __shfl_xor(rounds, 32, 64));
        float erv = valid ? er8[(size_t)v * 8 + head] : 0.f;
        float acc[8] = {0.f, 0.f, 0.f, 0.f, 0.f, 0.f, 0.f, 0.f};
        float lsum = 0.f;
        // prefetch+weight group 0
        int pk;
        {
            int pidx = beg + j;
            bool ok = pidx < end;
            int s = ok ? csr_src[pidx] : 0;
            float el = ok ? el8[(size_t)s * 8 + head] : 0.f;
            float lg = el + erv;
            lg = (lg >= 0.f) ? lg : 0.2f * lg;
            float wv = ok ? __expf(lg) : 0.f;
            lsum += wv;
            U16 uu; uu.h = (f16)wv;
            pk = s | ((int)uu.u << 16);
        }
        for (int base = 0; base < rounds; base += 8) {
            int pk_nxt;
            {   // next group's weight: loads+exp hidden under gathers below
                int pn = beg + base + 8 + j;
                bool ok = pn < end;
                int s = ok ? csr_src[pn] : 0;
                float el = ok ? el8[(size_t)s * 8 + head] : 0.f;
                float lg = el + erv;
                lg = (lg >= 0.f) ? lg : 0.2f * lg;
                float wv = ok ? __expf(lg) : 0.f;
                lsum += wv;
                U16 uu; uu.h = (f16)wv;
                pk_nxt = s | ((int)uu.u << 16);
            }
#pragma unroll
            for (int hg = 0; hg < 2; ++hg) {
                int cb4 = clbase + hg * 4;
                int p0 = __shfl(pk, cb4 + 0, 64);
                int p1 = __shfl(pk, cb4 + 1, 64);
                int p2 = __shfl(pk, cb4 + 2, 64);
                int p3 = __shfl(pk, cb4 + 3, 64);
                half8 f0 = *(const half8*)&fc[(size_t)(p0 & 0xFFFF) * 64 + coff];
                half8 f1 = *(const half8*)&fc[(size_t)(p1 & 0xFFFF) * 64 + coff];
                half8 f2 = *(const half8*)&fc[(size_t)(p2 & 0xFFFF) * 64 + coff];
                half8 f3 = *(const half8*)&fc[(size_t)(p3 & 0xFFFF) * 64 + coff];
                U16 u0; u0.u = (unsigned short)((unsigned)p0 >> 16); float w0 = (float)u0.h;
                U16 u1; u1.u = (unsigned short)((unsigned)p1 >> 16); float w1 = (float)u1.h;
                U16 u2; u2.u = (unsigned short)((unsigned)p2 >> 16); float w2 = (float)u2.h;
                U16 u3; u3.u = (unsigned short)((unsigned)p3 >> 16); float w3 = (float)u3.h;
#pragma unroll
                for (int k = 0; k < 8; ++k) acc[k] += w0 * (float)f0[k];
#pragma unroll
                for (int k = 0; k < 8; ++k) acc[k] += w1 * (float)f1[k];
#pragma unroll
                for (int k = 0; k < 8; ++k) acc[k] += w2 * (float)f2[k];
#pragma unroll
                for (int k = 0; k < 8; ++k) acc[k] += w3 * (float)f3[k];
            }
            pk = pk_nxt;
        }
        // intra-cluster sum of full-precision weights -> softmax denominator
        lsum += __shfl_xor(lsum, 1, 64);
        lsum += __shfl_xor(lsum, 2, 64);
        lsum += __shfl_xor(lsum, 4, 64);
        if (valid) {
            float inv = 1.f / fmaxf(lsum, 1e-9f);
            float ox[8];
#pragma unroll
            for (int k = 0; k < 8; ++k) ox[k] = acc[k] * inv;
            size_t base = (size_t)v * width + cb;
            if (res) {
                half8 rr = *(const half8*)&res[base];
#pragma unroll
                for (int k = 0; k < 8; ++k) ox[k] += (float)rr[k];
            }
            ox[0] += bv0.x; ox[1] += bv0.y; ox[2] += bv0.z; ox[3] += bv0.w;
            ox[4] += bv1.x; ox[5] += bv1.y; ox[6] += bv1.z; ox[7] += bv1.w;
            if (act) {
#pragma unroll
                for (int k = 0; k < 8; ++k)
                    ox[k] = (ox[k] > 0.f) ? ox[k] : expm1f(ox[k]);
            }
            if (out16) {
                half8 o;
#pragma unroll
                for (int k = 0; k < 8; ++k) o[k] = (f16)ox[k];
                *(half8*)&out16[base] = o;
            } else {
                *(float4*)&out32[base]     = make_float4(ox[0], ox[1], ox[2], ox[3]);
                *(float4*)&out32[base + 4] = make_float4(ox[4], ox[5], ox[6], ox[7]);
            }
        }
    }
}

__global__ __launch_bounds__(256, 6) void agg_chunk_kernel(
        const f16* __restrict__ featc, const int* __restrict__ csr_src,
        const float* __restrict__ el8, const float* __restrict__ er8,
        const int* __restrict__ row_off,
        const f16* __restrict__ res, const float* __restrict__ bias,
        f16* __restrict__ out16, float* __restrict__ out32,
        int n, int nchunks, int width, int E, int act) {
    int wid = threadIdx.x >> 6, lane = threadIdx.x & 63;
    int b = blockIdx.x;
    {   // phase 1: chunks 0..7
        int chunk = b & 7;
        agg_chunk_body(featc + (size_t)chunk * CHSTRIDE, csr_src, el8, er8,
                       chunk >> 1, row_off, res, bias, out16, out32,
                       n, width, act, chunk, (b >> 3) * 4 + wid, 1024, lane);
    }
    if (nchunks > 8) {   // phase 2: chunks 8..11
        int chunk = 8 + (b & 3);
        if (chunk < nchunks)
            agg_chunk_body(featc + (size_t)chunk * CHSTRIDE, csr_src, el8, er8,
                           chunk >> 1, row_off, res, bias, out16, out32,
                           n, width, act, chunk, (b >> 2) * 4 + wid, 2048, lane);
    }
}

// ------------------- pooling: segmented (gid is sorted) --------------------
// head-mean of x3 + folded residual resm (f16, already includes 1/6 factor)

__global__ __launch_bounds__(128) void mean_pool_kernel(const float* __restrict__ x3,
                                                        const f16* __restrict__ resm,
                                                        float* __restrict__ local, int n) {
    int v = blockIdx.x;
    int d = threadIdx.x;
    const float* p = x3 + (size_t)v * 768;
    float s = 0.f;
#pragma unroll
    for (int h = 0; h < 6; ++h) s += p[h * 128 + d];
    local[(size_t)v * 128 + d] = s * (1.f / 6.f) + (float)resm[(size_t)v * 128 + d];
}

// ---------- per-graph mean + final MLP fused (gid sorted) ------------------

__global__ __launch_bounds__(1024) void graph_pool_kernel(const float* __restrict__ local,
                                                          const int* __restrict__ gstart,
                                                          const float* __restrict__ Wm,
                                                          const float* __restrict__ bm,
                                                          float* __restrict__ gout) {
    __shared__ float buf[8][128];
    __shared__ float p[128];
    int g = blockIdx.x;
    int t = threadIdx.x;
    int c = t & 127;
    int sub = t >> 7;                 // 0..7
    int beg = gstart[g], end = gstart[g + 1];
    float s = 0.f;
    for (int v = beg + sub; v < end; v += 8) s += local[(size_t)v * 128 + c];
    buf[sub][c] = s;
    __syncthreads();
    if (sub == 0) {
        float tot = 0.f;
#pragma unroll
        for (int k = 0; k < 8; ++k) tot += buf[k][c];
        float cntf = fmaxf((float)(end - beg), 1.f);
        p[c] = tot / cntf;
    }
    __syncthreads();
    if (t < 128) {
        float s2 = 0.f;
#pragma unroll 16
        for (int k = 0; k < 128; ++k) s2 += p[k] * Wm[k * 128 + t];
        gout[g * 128 + t] = s2 + bm[t];
    }
}

// --------------------------------- driver ----------------------------------

extern "C" void kernel_launch(void* const* d_in, const int* in_sizes, int n_in,
                              void* d_out, int out_size, void* d_ws, size_t ws_size,
                              hipStream_t stream) {
    const float* h     = (const float*)d_in[0];
    const int*   src   = (const int*)d_in[2];
    const int*   dst   = (const int*)d_in[3];
    const int*   gid   = (const int*)d_in[4];
    const float* W0    = (const float*)d_in[5];
    const float* al0   = (const float*)d_in[6];
    const float* ar0   = (const float*)d_in[7];
    const float* b0    = (const float*)d_in[8];
    const float* W1    = (const float*)d_in[9];
    const float* al1   = (const float*)d_in[10];
    const float* ar1   = (const float*)d_in[11];
    const float* b1    = (const float*)d_in[12];
    const float* W2    = (const float*)d_in[13];
    const float* al2   = (const float*)d_in[14];
    const float* ar2   = (const float*)d_in[15];
    const float* b2    = (const float*)d_in[16];
    const float* resW2 = (const float*)d_in[17];
    const float* Wm    = (const float*)d_in[18];
    const float* bm    = (const float*)d_in[19];

    const int n = in_sizes[0] / 128;   // 20000
    const int E = in_sizes[2];         // 320000

    size_t off = 0;
    auto take = [&](size_t bytes) -> void* {
        void* p = (char*)d_ws + off;
        off = (off + bytes + 255) & ~(size_t)255;
        return p;
    };
    f16* h16     = (f16*)take((size_t)M_PAD * 128 * 2);
    f16* Wt0     = (f16*)take((size_t)512 * 128 * 2);
    f16* Wt1     = (f16*)take((size_t)512 * 512 * 2);
    f16* Wt2cat  = (f16*)take((size_t)896 * 512 * 2);     // [W2^T (768) ; resW2m^T (128)]
    f16* featc   = (f16*)take((size_t)12 * CHSTRIDE * 2); // chunk-major feat
    f16* resm    = (f16*)take((size_t)M_PAD * 128 * 2);   // folded mean residual
    f16* x1_16   = (f16*)take((size_t)M_PAD * 512 * 2);
    f16* x2_16   = (f16*)take((size_t)M_PAD * 512 * 2);
    float* x3    = (float*)take((size_t)n * 768 * 4);     // fp32 head outputs L2
    float* el8   = (float*)take((size_t)n * 8 * 4);
    float* er8   = (float*)take((size_t)n * 8 * 4);
    int* deg     = (int*)take((size_t)2 * n * 4);  // deg | fillc contiguous
    int* fillc   = deg + n;
    int* row_off = (int*)take((size_t)(n + 1) * 4);
    int* csr_src = (int*)take((size_t)E * 4);
    int* gstart  = (int*)take(65 * 4);

    float* out_local  = (float*)d_out;
    float* out_global = (float*)d_out + (size_t)n * 128;

    // all independent preprocessing in ONE dispatch (incl. deg|fillc zeroing)
    prep_kernel<<<3560, 256, 0, stream>>>(h, h16, x1_16, x2_16, W0, Wt0, W1, Wt1,
                                          W2, resW2, Wt2cat, deg, n);

    deg_kernel<<<(E + 255) / 256, 256, 0, stream>>>(dst, deg, E);
    scan_kernel<<<1, 1024, 0, stream>>>(deg, row_off, gid, gstart, n);
    fill_kernel<<<(E + 255) / 256, 256, 0, stream>>>(src, dst, row_off, fillc, csr_src, E);

    const int gy = M_PAD / 64;          // 314 row panels (BM=64)

    // --- layer 0: feat = h16 @ W0 (8 chunks) + fused logits, H=4, elu ---
    gemm16_kernel<<<dim3(512 / 128, gy), 256, 0, stream>>>(h16, Wt0, featc, nullptr,
                                                           al0, ar0, el8, er8, 512, 128, 512, 4, n);
    agg_chunk_kernel<<<2048, 256, 0, stream>>>(featc, csr_src, el8, er8, row_off,
                                               nullptr, b0, x1_16, nullptr, n, 8, 512, E, 1);
    // --- layer 1: feat = x1 @ W1 (8 chunks) + fused logits, identity res, elu ---
    gemm16_kernel<<<dim3(512 / 128, gy), 256, 0, stream>>>(x1_16, Wt1, featc, nullptr,
                                                           al1, ar1, el8, er8, 512, 512, 512, 4, n);
    agg_chunk_kernel<<<2048, 256, 0, stream>>>(featc, csr_src, el8, er8, row_off,
                                               x1_16, b1, x2_16, nullptr, n, 8, 512, E, 1);
    // --- layer 2: [feat(12 chunks) | resm] = x2 @ [W2 | resW2m] + fused logits,
    //     H=6; residual folded into the 128 mean-residual columns ---
    gemm16_kernel<<<dim3(896 / 128, gy), 256, 0, stream>>>(x2_16, Wt2cat, featc, resm,
                                                           al2, ar2, el8, er8, 896, 512, 768, 6, n);
    agg_chunk_kernel<<<2048, 256, 0, stream>>>(featc, csr_src, el8, er8, row_off,
                                               nullptr, b2, nullptr, x3, n, 12, 768, E, 0);
    // --- pooling epilogue (atomic-free) ---
    mean_pool_kernel<<<n, 128, 0, stream>>>(x3, resm, out_local, n);
    graph_pool_kernel<<<64, 1024, 0, stream>>>(out_local, gstart, Wm, bm, out_global);
}

// Round 13
// 497.962 us; speedup vs baseline: 1.1007x; 1.1007x over previous
//
#include <hip/hip_runtime.h>
#include <math.h>

// ---------------------------------------------------------------------------
// GAT 3-layer + pooling. XCD-sharded gather + XOR-swizzled GEMM LDS.
//  - agg v12 (r12's softmax-fusion REVERTED: per-chunk el8 gathers exploded
//    FETCH 127->208MB, 505->548us. Back to r8 body + separate edge_weight).
//  - x3 in F16 (this round): L2 agg stores via the proven out16 path
//    (dense 16B/lane); mean_pool reads f16. Saves 30.7MB write + 30.7MB
//    read. Head-mean averages the f16 rounding noise (~2^-11 abs).
//  - prep v1 (r11): all independent preprocessing in ONE dispatch.
//  - GEMM v4 (r10): BM=64 x BN=128 tiles; 2x2 waves over 32x64 sub-tiles;
//    2-buffer STAGE-before-compute; m204 XCD swizzle.
//  - L2 residual FOLDED (r8): mean_h(res2) == x2 @ resW2m; L2 GEMM N=896.
//  - graph_pool: 1024-thr 8-way reduce, final MLP fused.
//  - feat CHUNK-MAJOR featc[chunk][node][64]; chunk=blockIdx%8 -> XCD-pinned L2.
//  - edge_weight v3: writes packed int32 (src|w16<<16) per head.
//  - attn logits fused in GEMM epilogue; pooling segmented (gid sorted).
// ---------------------------------------------------------------------------

typedef _Float16 f16;
typedef __attribute__((ext_vector_type(8))) _Float16 half8;
typedef __attribute__((ext_vector_type(4))) _Float16 half4;
typedef __attribute__((ext_vector_type(4))) float float4v;

union U16 { unsigned short u; _Float16 h; };

#define M_PAD 20096        // 20000 rounded up to 128 (and to 64)
#define CHSTRIDE ((size_t)M_PAD * 64)

__device__ inline void gload_lds16(const void* g, void* l) {
    __builtin_amdgcn_global_load_lds((const __attribute__((address_space(1))) unsigned*)g,
                                     (__attribute__((address_space(3))) unsigned*)l,
                                     16, 0, 0);
}

// ----------------------------- CSR construction ---------------------------

__global__ __launch_bounds__(256) void deg_kernel(const int* __restrict__ dst,
                                                  int* __restrict__ deg, int E) {
    int e = blockIdx.x * 256 + threadIdx.x;
    if (e < E) atomicAdd(&deg[dst[e]], 1);
}

// scan + (fused) graph-segment binary search
__global__ __launch_bounds__(1024) void scan_kernel(const int* __restrict__ deg,
                                                    int* __restrict__ row_off,
                                                    const int* __restrict__ gid,
                                                    int* __restrict__ gstart, int n) {
    __shared__ int sums[1024];
    int t = threadIdx.x;
    if (t <= 64) {
        int g = t, lo = 0, hi = n;
        while (lo < hi) {
            int mid = (lo + hi) >> 1;
            if (gid[mid] < g) lo = mid + 1; else hi = mid;
        }
        gstart[g] = lo;
    }
    int CH = (n + 1023) >> 10;
    int base = t * CH;
    int s = 0;
    for (int i = 0; i < CH; ++i) { int idx = base + i; if (idx < n) s += deg[idx]; }
    sums[t] = s;
    __syncthreads();
    for (int off = 1; off < 1024; off <<= 1) {
        int v = (t >= off) ? sums[t - off] : 0;
        __syncthreads();
        sums[t] += v;
        __syncthreads();
    }
    int run = (t == 0) ? 0 : sums[t - 1];
    for (int i = 0; i < CH; ++i) {
        int idx = base + i;
        if (idx < n) { row_off[idx] = run; run += deg[idx]; }
    }
    if (t == 1023) row_off[n] = run;
}

__global__ __launch_bounds__(256) void fill_kernel(const int* __restrict__ src,
                                                   const int* __restrict__ dst,
                                                   const int* __restrict__ row_off,
                                                   int* __restrict__ fill,
                                                   int* __restrict__ csr_src, int E) {
    int e = blockIdx.x * 256 + threadIdx.x;
    if (e < E) {
        int d = dst[e];
        int pos = row_off[d] + atomicAdd(&fill[d], 1);
        csr_src[pos] = src[e];
    }
}

// ------------------- fused preprocessing (one dispatch) --------------------
// blockIdx ranges:
//   [0,2512)      cvt_pad: h (fp32) -> h16, zero rows >= n   (M_PAD*128/1024)
//   [2512,2560)   zero_pad rows [n,M_PAD) of x1,x2 (512 cols)
//   [2560,2624)   transpose W0  (512/32 x 128/32)
//   [2624,2880)   transpose W1  (512/32 x 512/32)
//   [2880,3264)   transpose W2  (768/32 x 512/32) -> Wt2cat[0:768]
//   [3264,3520)   fold_res: resW2m^T -> Wt2cat[768:896]
//   [3520,3560)   zero deg|fillc (2n ints, int4)

__global__ __launch_bounds__(256) void prep_kernel(
        const float* __restrict__ h, f16* __restrict__ h16,
        f16* __restrict__ x1, f16* __restrict__ x2,
        const float* __restrict__ W0, f16* __restrict__ Wt0,
        const float* __restrict__ W1, f16* __restrict__ Wt1,
        const float* __restrict__ W2, const float* __restrict__ resW2,
        f16* __restrict__ Wt2cat,
        int* __restrict__ deg2, int n) {
    __shared__ float tile[32][33];
    int b = blockIdx.x;
    int t = threadIdx.x;
    if (b < 2512) {               // cvt_pad
        long i = ((long)b * 256 + t) * 4;
        long nv = (long)n * 128;
        float4 v = make_float4(0.f, 0.f, 0.f, 0.f);
        if (i < nv) v = *(const float4*)&h[i];
        half4 o; o[0] = (f16)v.x; o[1] = (f16)v.y; o[2] = (f16)v.z; o[3] = (f16)v.w;
        *(half4*)&h16[i] = o;
        return;
    }
    b -= 2512;
    if (b < 48) {                 // zero_pad x1/x2
        int idx = (b * 256 + t) * 4;
        int total = (M_PAD - n) * 512;
        if (idx < total) {
            half4 z; z[0] = (f16)0.f; z[1] = (f16)0.f; z[2] = (f16)0.f; z[3] = (f16)0.f;
            *(half4*)&x1[(size_t)n * 512 + idx] = z;
            *(half4*)&x2[(size_t)n * 512 + idx] = z;
        }
        return;
    }
    b -= 48;
    {   // transposes: W0 (64 blk), W1 (256 blk), W2 (384 blk)
        const float* W = nullptr; f16* Wt = nullptr;
        int K = 0, N = 0, bx = 0, by = 0;
        bool dotr = false;
        if (b < 64)        { W = W0; Wt = Wt0;    K = 128; N = 512; bx = b & 15;  by = b >> 4; dotr = true; }
        else if (b < 320)  { int r = b - 64;  W = W1; Wt = Wt1;    K = 512; N = 512; bx = r & 15;  by = r >> 4; dotr = true; }
        else if (b < 704)  { int r = b - 320; W = W2; Wt = Wt2cat; K = 512; N = 768; bx = r % 24;  by = r / 24; dotr = true; }
        if (dotr) {
            int tx = t & 31, ty = t >> 5;
            int n0 = bx * 32, k0 = by * 32;
#pragma unroll
            for (int i = 0; i < 32; i += 8)
                tile[ty + i][tx] = W[(size_t)(k0 + ty + i) * N + n0 + tx];
            __syncthreads();
#pragma unroll
            for (int i = 0; i < 32; i += 8)
                Wt[(size_t)(n0 + ty + i) * K + k0 + tx] = (f16)tile[tx][ty + i];
            return;
        }
    }
    b -= 704;
    if (b < 256) {                // fold_res
        int idx = b * 256 + t;
        int d = idx >> 9;          // 0..127
        int k = idx & 511;         // 0..511
        float s = 0.f;
#pragma unroll
        for (int hh = 0; hh < 6; ++hh) s += resW2[(size_t)k * 768 + hh * 128 + d];
        Wt2cat[(size_t)(768 + d) * 512 + k] = (f16)(s * (1.f / 6.f));
        return;
    }
    b -= 256;
    {                             // zero deg|fillc
        int idx = (b * 256 + t) * 4;
        if (idx < 2 * n) *(int4*)&deg2[idx] = make_int4(0, 0, 0, 0);
    }
}

// ------------------------------ fp16 MFMA GEMM -----------------------------
// BM=64 x BN=128 tile, 4 waves as 2(M) x 2(N) over 32x64 sub-tiles.
// LDS: As[64][32], Bs[128][32] per buffer, octets XOR-swizzled within rows:
//   slot s of row r holds global octet s ^ ((r>>1)&3).
// Staging: lane t -> row t>>2, slot t&3 -> stages octet (t&3)^((row>>1)&3);
//   A = 1 gload/thread (64 rows), B = 2 gloads (128 rows).
// Frag read: lane (ml,q) reads slot q^((ml>>1)&3); swizzle invariant under
//   +16/+32/+64 row offsets (all ≡ 0 mod 4 after >>1).
// Pipeline: double-buffered; STAGE(t+1) issued before compute(t); one barrier
// per K-step.

#define STAGE(buf, k0) do {                                   \
    f16* a_ = As + (buf) * 2048 + t * 8;                      \
    f16* b_ = Bs + (buf) * 4096 + t * 8;                      \
    gload_lds16(ag0 + (k0), a_);                              \
    gload_lds16(bg0 + (k0), b_);                              \
    gload_lds16(bg1 + (k0), b_ + 2048);                       \
} while (0)

__global__ __launch_bounds__(256) void gemm16_kernel(const f16* __restrict__ A,
                                                     const f16* __restrict__ Bt,
                                                     f16* __restrict__ Cc,
                                                     f16* __restrict__ Cr,
                                                     const float* __restrict__ al,
                                                     const float* __restrict__ ar,
                                                     float* __restrict__ el8,
                                                     float* __restrict__ er8,
                                                     int N, int K, int nchunk,
                                                     int nheads, int nvalid) {
    __shared__ f16 As[2 * 64 * 32];
    __shared__ f16 Bs[2 * 128 * 32];
    __shared__ float elds[2][2][64];   // [el/er][wn-half][row]
    int t = threadIdx.x;
    int w = t >> 6;
    int l = t & 63;

    // m204 bijective XCD swizzle
    int gx = gridDim.x;
    int nwg = gx * gridDim.y;
    int wg = blockIdx.y * gx + blockIdx.x;
    int qq = nwg >> 3, rr = nwg & 7;
    int xcd = wg & 7, idx = wg >> 3;
    int swz = (xcd < rr ? xcd * (qq + 1) : rr * (qq + 1) + (xcd - rr) * qq) + idx;
    int bxi = swz % gx;
    int byi = swz / gx;

    size_t bm = (size_t)byi * 64;
    int bn = bxi * 128;
    int wm = (w & 1) * 32;
    int wn = (w >> 1) * 64;

    int srow = t >> 2;                        // 0..63
    int sq = (t & 3) ^ ((srow >> 1) & 3);     // swizzled octet to stage
    const f16* ag0 = A + (bm + srow) * K + sq * 8;
    const f16* bg0 = Bt + (size_t)(bn + srow) * K + sq * 8;
    const f16* bg1 = Bt + (size_t)(bn + 64 + srow) * K + sq * 8;  // (64+r)>>1 ≡ r>>1 mod 4

    float4v acc[2][4];
#pragma unroll
    for (int i = 0; i < 2; ++i)
#pragma unroll
        for (int j = 0; j < 4; ++j) acc[i][j] = (float4v)(0.f);

    int ml = l & 15, q = l >> 4;
    int sslot = (q ^ ((ml >> 1) & 3)) * 8;    // swizzled read slot (f16 offset)
    int apoff = (wm + ml) * 32 + sslot;
    int bpoff = (wn + ml) * 32 + sslot;

    // prologue: stage tile 0, drain, flip into main loop
    STAGE(0, 0);
    __syncthreads();
    int cur = 0;
    for (int k0 = 0; k0 < K; k0 += 32) {
        if (k0 + 32 < K) STAGE(cur ^ 1, k0 + 32);   // issue next-tile loads FIRST
        const f16* ap = As + cur * 2048 + apoff;
        const f16* bp = Bs + cur * 4096 + bpoff;
        half8 af[2], bf[4];
#pragma unroll
        for (int mt = 0; mt < 2; ++mt) af[mt] = *(const half8*)(ap + mt * 16 * 32);
#pragma unroll
        for (int nt = 0; nt < 4; ++nt) bf[nt] = *(const half8*)(bp + nt * 16 * 32);
#pragma unroll
        for (int mt = 0; mt < 2; ++mt)
#pragma unroll
            for (int nt = 0; nt < 4; ++nt)
                acc[mt][nt] = __builtin_amdgcn_mfma_f32_16x16x32_f16(bf[nt], af[mt],
                                                                     acc[mt][nt], 0, 0, 0);
        __syncthreads();
        cur ^= 1;
    }
    // C stores
#pragma unroll
    for (int mt = 0; mt < 2; ++mt) {
        size_t row = bm + wm + mt * 16 + ml;
#pragma unroll
        for (int nt = 0; nt < 4; ++nt) {
            half4 hv;
#pragma unroll
            for (int r = 0; r < 4; ++r) hv[r] = (f16)acc[mt][nt][r];
            int col = bn + wn + nt * 16 + q * 4;
            if (col < nchunk) {
                *(half4*)&Cc[(size_t)(col >> 6) * CHSTRIDE + row * 64 + (col & 63)] = hv;
            } else {
                *(half4*)&Cr[row * (size_t)(N - nchunk) + (col - nchunk)] = hv;
            }
        }
    }
    // fused attention logits (block column == one head)
    if (al != nullptr && bn < nheads * 128) {
        int hh = bn >> 7;
        float4 a4[4], r4[4];
#pragma unroll
        for (int nt = 0; nt < 4; ++nt) {
            int ci = hh * 128 + wn + nt * 16 + q * 4;
            a4[nt] = *(const float4*)&al[ci];
            r4[nt] = *(const float4*)&ar[ci];
        }
        int wnidx = wn >> 6;
#pragma unroll
        for (int mt = 0; mt < 2; ++mt) {
            float ep = 0.f, rp = 0.f;
#pragma unroll
            for (int nt = 0; nt < 4; ++nt) {
                ep += acc[mt][nt][0] * a4[nt].x + acc[mt][nt][1] * a4[nt].y
                    + acc[mt][nt][2] * a4[nt].z + acc[mt][nt][3] * a4[nt].w;
                rp += acc[mt][nt][0] * r4[nt].x + acc[mt][nt][1] * r4[nt].y
                    + acc[mt][nt][2] * r4[nt].z + acc[mt][nt][3] * r4[nt].w;
            }
            ep += __shfl_xor(ep, 16, 64); ep += __shfl_xor(ep, 32, 64);
            rp += __shfl_xor(rp, 16, 64); rp += __shfl_xor(rp, 32, 64);
            if (q == 0) {
                elds[0][wnidx][wm + mt * 16 + ml] = ep;
                elds[1][wnidx][wm + mt * 16 + ml] = rp;
            }
        }
        __syncthreads();
        if (((t >> 6) & 1) == 0) {
            int row = t & 63, which = t >> 7;
            long gv = (long)bm + row;
            if (gv < nvalid) {
                float vs = elds[which][0][row] + elds[which][1][row];
                if (which == 0) el8[gv * 8 + hh] = vs;
                else            er8[gv * 8 + hh] = vs;
            }
        }
    }
}

// ------------------------ edge softmax weights v3 --------------------------
// Writes PACKED int32 per (head, edge): src | (f16-bits(w) << 16).

__global__ __launch_bounds__(256, 8) void edge_weight_kernel(
        const float* __restrict__ el8, const float* __restrict__ er8,
        const int* __restrict__ row_off, const int* __restrict__ csr_src,
        int* __restrict__ wp, float* __restrict__ inv8,
        int H, int n, int E) {
    int wid = threadIdx.x >> 6, lane = threadIdx.x & 63;
    int c2 = lane >> 4;
    int sl = lane & 15;
    int v = blockIdx.x * 16 + wid * 4 + c2;
    if (v >= n) return;
    float era[6];
    {
        float4 a = *(const float4*)&er8[(size_t)v * 8];
        float2 b = *(const float2*)&er8[(size_t)v * 8 + 4];
        era[0] = a.x; era[1] = a.y; era[2] = a.z; era[3] = a.w;
        era[4] = b.x; era[5] = b.y;
    }
    int beg = row_off[v], end = row_off[v + 1];
    float lsum[6] = {0.f, 0.f, 0.f, 0.f, 0.f, 0.f};
    for (int pos = beg; pos < end; pos += 16) {
        int cnt = min(16, end - pos);
        int s_l = (sl < cnt) ? csr_src[pos + sl] : 0;
        float4 a = *(const float4*)&el8[(size_t)s_l * 8];
        float2 bq = *(const float2*)&el8[(size_t)s_l * 8 + 4];
        float ee[6] = {a.x, a.y, a.z, a.w, bq.x, bq.y};
#pragma unroll
        for (int h = 0; h < 6; ++h) {
            if (h < H) {
                float lg = ee[h] + era[h];
                lg = (lg >= 0.f) ? lg : 0.2f * lg;
                float wv = __expf(lg);
                if (sl >= cnt) wv = 0.f;
                lsum[h] += wv;
                if (sl < cnt) {
                    U16 uu; uu.h = (f16)wv;
                    wp[(size_t)h * E + pos + sl] = s_l | ((int)uu.u << 16);
                }
            }
        }
    }
#pragma unroll
    for (int h = 0; h < 6; ++h)
#pragma unroll
        for (int off = 8; off >= 1; off >>= 1)
            lsum[h] += __shfl_xor(lsum[h], off, 64);
    if (sl == 0) {
#pragma unroll
        for (int h = 0; h < 6; ++h)
            if (h < H) inv8[(size_t)v * 8 + h] = 1.f / fmaxf(lsum[h], 1e-9f);
    }
}

// --- chunk-sharded aggregation (r8 body: packed edges, 4-wide, prefetch) ---

__device__ __forceinline__ void agg_chunk_body(
        const f16* __restrict__ fc, const int* __restrict__ wp,
        const float* __restrict__ inv8, int head,
        const int* __restrict__ row_off,
        const f16* __restrict__ res, const float* __restrict__ bias,
        f16* __restrict__ out16, float* __restrict__ out32,
        int n, int width, int act, int chunk,
        int wave_id, int wavestride, int lane) {
    int c = lane >> 3;
    int j = lane & 7;
    int coff = j * 8;
    int cb = chunk * 64 + coff;
    float4 bv0 = *(const float4*)&bias[cb];
    float4 bv1 = *(const float4*)&bias[cb + 4];
    int clbase = lane & 56;

    for (int v0 = wave_id * 8; v0 < n; v0 += wavestride * 8) {
        int v = v0 + c;
        bool valid = (v < n);
        int beg = 0, end = 0;
        if (valid) { beg = row_off[v]; end = row_off[v + 1]; }
        int rounds = end - beg;
        rounds = max(rounds, __shfl_xor(rounds, 8, 64));
        rounds = max(rounds, __shfl_xor(rounds, 16, 64));
        rounds = max(rounds, __shfl_xor(rounds, 32, 64));
        float acc[8] = {0.f, 0.f, 0.f, 0.f, 0.f, 0.f, 0.f, 0.f};
        // lane j holds packed edge (group_base + j); prefetch next group's
        // word while processing the current 8 edges (two 4-wide half-groups).
        int pidx = beg + j;
        int pk = (pidx < end) ? wp[pidx] : 0;
        for (int base = 0; base < rounds; base += 8) {
            int pn = beg + base + 8 + j;
            int pk_nxt = (pn < end) ? wp[pn] : 0;   // hidden under gathers below
#pragma unroll
            for (int hg = 0; hg < 2; ++hg) {
                int cb4 = clbase + hg * 4;
                int p0 = __shfl(pk, cb4 + 0, 64);
                int p1 = __shfl(pk, cb4 + 1, 64);
                int p2 = __shfl(pk, cb4 + 2, 64);
                int p3 = __shfl(pk, cb4 + 3, 64);
                half8 f0 = *(const half8*)&fc[(size_t)(p0 & 0xFFFF) * 64 + coff];
                half8 f1 = *(const half8*)&fc[(size_t)(p1 & 0xFFFF) * 64 + coff];
                half8 f2 = *(const half8*)&fc[(size_t)(p2 & 0xFFFF) * 64 + coff];
                half8 f3 = *(const half8*)&fc[(size_t)(p3 & 0xFFFF) * 64 + coff];
                U16 u0; u0.u = (unsigned short)((unsigned)p0 >> 16); float w0 = (float)u0.h;
                U16 u1; u1.u = (unsigned short)((unsigned)p1 >> 16); float w1 = (float)u1.h;
                U16 u2; u2.u = (unsigned short)((unsigned)p2 >> 16); float w2 = (float)u2.h;
                U16 u3; u3.u = (unsigned short)((unsigned)p3 >> 16); float w3 = (float)u3.h;
#pragma unroll
                for (int k = 0; k < 8; ++k) acc[k] += w0 * (float)f0[k];
#pragma unroll
                for (int k = 0; k < 8; ++k) acc[k] += w1 * (float)f1[k];
#pragma unroll
                for (int k = 0; k < 8; ++k) acc[k] += w2 * (float)f2[k];
#pragma unroll
                for (int k = 0; k < 8; ++k) acc[k] += w3 * (float)f3[k];
            }
            pk = pk_nxt;
        }
        if (valid) {
            float inv = inv8[(size_t)v * 8 + head];
            float ox[8];
#pragma unroll
            for (int k = 0; k < 8; ++k) ox[k] = acc[k] * inv;
            size_t base = (size_t)v * width + cb;
            if (res) {
                half8 rr = *(const half8*)&res[base];
#pragma unroll
                for (int k = 0; k < 8; ++k) ox[k] += (float)rr[k];
            }
            ox[0] += bv0.x; ox[1] += bv0.y; ox[2] += bv0.z; ox[3] += bv0.w;
            ox[4] += bv1.x; ox[5] += bv1.y; ox[6] += bv1.z; ox[7] += bv1.w;
            if (act) {
#pragma unroll
                for (int k = 0; k < 8; ++k)
                    ox[k] = (ox[k] > 0.f) ? ox[k] : expm1f(ox[k]);
            }
            if (out16) {
                half8 o;
#pragma unroll
                for (int k = 0; k < 8; ++k) o[k] = (f16)ox[k];
                *(half8*)&out16[base] = o;
            } else {
                *(float4*)&out32[base]     = make_float4(ox[0], ox[1], ox[2], ox[3]);
                *(float4*)&out32[base + 4] = make_float4(ox[4], ox[5], ox[6], ox[7]);
            }
        }
    }
}

__global__ __launch_bounds__(256, 6) void agg_chunk_kernel(
        const f16* __restrict__ featc, const int* __restrict__ wp,
        const float* __restrict__ inv8,
        const int* __restrict__ row_off,
        const f16* __restrict__ res, const float* __restrict__ bias,
        f16* __restrict__ out16, float* __restrict__ out32,
        int n, int nchunks, int width, int E, int act) {
    int wid = threadIdx.x >> 6, lane = threadIdx.x & 63;
    int b = blockIdx.x;
    {   // phase 1: chunks 0..7
        int chunk = b & 7;
        agg_chunk_body(featc + (size_t)chunk * CHSTRIDE, wp + (size_t)(chunk >> 1) * E,
                       inv8, chunk >> 1, row_off, res, bias, out16, out32,
                       n, width, act, chunk, (b >> 3) * 4 + wid, 1024, lane);
    }
    if (nchunks > 8) {   // phase 2: chunks 8..11
        int chunk = 8 + (b & 3);
        if (chunk < nchunks)
            agg_chunk_body(featc + (size_t)chunk * CHSTRIDE, wp + (size_t)(chunk >> 1) * E,
                           inv8, chunk >> 1, row_off, res, bias, out16, out32,
                           n, width, act, chunk, (b >> 2) * 4 + wid, 2048, lane);
    }
}

// ------------------- pooling: segmented (gid is sorted) --------------------
// head-mean of f16 x3 + folded residual resm (f16, already includes 1/6)

__global__ __launch_bounds__(128) void mean_pool_kernel(const f16* __restrict__ x3,
                                                        const f16* __restrict__ resm,
                                                        float* __restrict__ local, int n) {
    int v = blockIdx.x;
    int d = threadIdx.x;
    const f16* p = x3 + (size_t)v * 768;
    float s = 0.f;
#pragma unroll
    for (int h = 0; h < 6; ++h) s += (float)p[h * 128 + d];
    local[(size_t)v * 128 + d] = s * (1.f / 6.f) + (float)resm[(size_t)v * 128 + d];
}

// ---------- per-graph mean + final MLP fused (gid sorted) ------------------

__global__ __launch_bounds__(1024) void graph_pool_kernel(const float* __restrict__ local,
                                                          const int* __restrict__ gstart,
                                                          const float* __restrict__ Wm,
                                                          const float* __restrict__ bm,
                                                          float* __restrict__ gout) {
    __shared__ float buf[8][128];
    __shared__ float p[128];
    int g = blockIdx.x;
    int t = threadIdx.x;
    int c = t & 127;
    int sub = t >> 7;                 // 0..7
    int beg = gstart[g], end = gstart[g + 1];
    float s = 0.f;
    for (int v = beg + sub; v < end; v += 8) s += local[(size_t)v * 128 + c];
    buf[sub][c] = s;
    __syncthreads();
    if (sub == 0) {
        float tot = 0.f;
#pragma unroll
        for (int k = 0; k < 8; ++k) tot += buf[k][c];
        float cntf = fmaxf((float)(end - beg), 1.f);
        p[c] = tot / cntf;
    }
    __syncthreads();
    if (t < 128) {
        float s2 = 0.f;
#pragma unroll 16
        for (int k = 0; k < 128; ++k) s2 += p[k] * Wm[k * 128 + t];
        gout[g * 128 + t] = s2 + bm[t];
    }
}

// --------------------------------- driver ----------------------------------

extern "C" void kernel_launch(void* const* d_in, const int* in_sizes, int n_in,
                              void* d_out, int out_size, void* d_ws, size_t ws_size,
                              hipStream_t stream) {
    const float* h     = (const float*)d_in[0];
    const int*   src   = (const int*)d_in[2];
    const int*   dst   = (const int*)d_in[3];
    const int*   gid   = (const int*)d_in[4];
    const float* W0    = (const float*)d_in[5];
    const float* al0   = (const float*)d_in[6];
    const float* ar0   = (const float*)d_in[7];
    const float* b0    = (const float*)d_in[8];
    const float* W1    = (const float*)d_in[9];
    const float* al1   = (const float*)d_in[10];
    const float* ar1   = (const float*)d_in[11];
    const float* b1    = (const float*)d_in[12];
    const float* W2    = (const float*)d_in[13];
    const float* al2   = (const float*)d_in[14];
    const float* ar2   = (const float*)d_in[15];
    const float* b2    = (const float*)d_in[16];
    const float* resW2 = (const float*)d_in[17];
    const float* Wm    = (const float*)d_in[18];
    const float* bm    = (const float*)d_in[19];

    const int n = in_sizes[0] / 128;   // 20000
    const int E = in_sizes[2];         // 320000

    size_t off = 0;
    auto take = [&](size_t bytes) -> void* {
        void* p = (char*)d_ws + off;
        off = (off + bytes + 255) & ~(size_t)255;
        return p;
    };
    f16* h16     = (f16*)take((size_t)M_PAD * 128 * 2);
    f16* Wt0     = (f16*)take((size_t)512 * 128 * 2);
    f16* Wt1     = (f16*)take((size_t)512 * 512 * 2);
    f16* Wt2cat  = (f16*)take((size_t)896 * 512 * 2);     // [W2^T (768) ; resW2m^T (128)]
    f16* featc   = (f16*)take((size_t)12 * CHSTRIDE * 2); // chunk-major feat
    f16* resm    = (f16*)take((size_t)M_PAD * 128 * 2);   // folded mean residual
    f16* x1_16   = (f16*)take((size_t)M_PAD * 512 * 2);
    f16* x2_16   = (f16*)take((size_t)M_PAD * 512 * 2);
    f16* x3h     = (f16*)take((size_t)n * 768 * 2);       // f16 head outputs L2
    int* wp      = (int*)take((size_t)6 * E * 4);         // packed (src | w16<<16)
    float* inv8  = (float*)take((size_t)n * 8 * 4);
    float* el8   = (float*)take((size_t)n * 8 * 4);
    float* er8   = (float*)take((size_t)n * 8 * 4);
    int* deg     = (int*)take((size_t)2 * n * 4);  // deg | fillc contiguous
    int* fillc   = deg + n;
    int* row_off = (int*)take((size_t)(n + 1) * 4);
    int* csr_src = (int*)take((size_t)E * 4);
    int* gstart  = (int*)take(65 * 4);

    float* out_local  = (float*)d_out;
    float* out_global = (float*)d_out + (size_t)n * 128;

    // all independent preprocessing in ONE dispatch (incl. deg|fillc zeroing)
    prep_kernel<<<3560, 256, 0, stream>>>(h, h16, x1_16, x2_16, W0, Wt0, W1, Wt1,
                                          W2, resW2, Wt2cat, deg, n);

    deg_kernel<<<(E + 255) / 256, 256, 0, stream>>>(dst, deg, E);
    scan_kernel<<<1, 1024, 0, stream>>>(deg, row_off, gid, gstart, n);
    fill_kernel<<<(E + 255) / 256, 256, 0, stream>>>(src, dst, row_off, fillc, csr_src, E);

    const int gy = M_PAD / 64;          // 314 row panels (BM=64)
    const int ew_blocks = (n + 15) / 16;

    // --- layer 0: feat = h16 @ W0 (8 chunks) + fused logits, H=4, elu ---
    gemm16_kernel<<<dim3(512 / 128, gy), 256, 0, stream>>>(h16, Wt0, featc, nullptr,
                                                           al0, ar0, el8, er8, 512, 128, 512, 4, n);
    edge_weight_kernel<<<ew_blocks, 256, 0, stream>>>(el8, er8, row_off, csr_src, wp, inv8, 4, n, E);
    agg_chunk_kernel<<<2048, 256, 0, stream>>>(featc, wp, inv8, row_off,
                                               nullptr, b0, x1_16, nullptr, n, 8, 512, E, 1);
    // --- layer 1: feat = x1 @ W1 (8 chunks) + fused logits, identity res, elu ---
    gemm16_kernel<<<dim3(512 / 128, gy), 256, 0, stream>>>(x1_16, Wt1, featc, nullptr,
                                                           al1, ar1, el8, er8, 512, 512, 512, 4, n);
    edge_weight_kernel<<<ew_blocks, 256, 0, stream>>>(el8, er8, row_off, csr_src, wp, inv8, 4, n, E);
    agg_chunk_kernel<<<2048, 256, 0, stream>>>(featc, wp, inv8, row_off,
                                               x1_16, b1, x2_16, nullptr, n, 8, 512, E, 1);
    // --- layer 2: [feat(12 chunks) | resm] = x2 @ [W2 | resW2m] + fused logits,
    //     H=6; residual folded into the 128 mean-residual columns ---
    gemm16_kernel<<<dim3(896 / 128, gy), 256, 0, stream>>>(x2_16, Wt2cat, featc, resm,
                                                           al2, ar2, el8, er8, 896, 512, 768, 6, n);
    edge_weight_kernel<<<ew_blocks, 256, 0, stream>>>(el8, er8, row_off, csr_src, wp, inv8, 6, n, E);
    agg_chunk_kernel<<<2048, 256, 0, stream>>>(featc, wp, inv8, row_off,
                                               nullptr, b2, x3h, nullptr, n, 12, 768, E, 0);
    // --- pooling epilogue (atomic-free) ---
    mean_pool_kernel<<<n, 128, 0, stream>>>(x3h, resm, out_local, n);
    graph_pool_kernel<<<64, 1024, 0, stream>>>(out_local, gstart, Wm, bm, out_global);
}